// Round 10
// baseline (226.939 us; speedup 1.0000x reference)
//
#include <hip/hip_runtime.h>

// Problem constants (SubOut_60206851555968): B=8, U=E=1024, D=P=256, fp32 in/out.
#define BDIM 8
#define UDIM 1024
#define EDIM 1024
#define DDIM 256
#define PDIM 256

typedef __attribute__((ext_vector_type(8))) short bf16x8;   // 8 bf16 = 4 VGPRs
typedef __attribute__((ext_vector_type(4))) float f32x4;    // clang ext_vector: legal in asm "v"
typedef __attribute__((ext_vector_type(4))) ushort u16x4;

__device__ __forceinline__ short f2bf(float x) {
    unsigned u = __float_as_uint(x);
    unsigned r = (u + 0x7FFFu + ((u >> 16) & 1u)) >> 16;   // RNE
    return (short)r;
}

// Async global->LDS DMA, 16B per lane. LDS dest = wave-uniform base + lane*16;
// global src is per-lane (swizzled/permuted LDS layouts = pre-permute the SOURCE).
__device__ __forceinline__ void dma16(const void* g, void* lds) {
    __builtin_amdgcn_global_load_lds(
        (const __attribute__((address_space(1))) unsigned*)g,
        (__attribute__((address_space(3))) unsigned*)lds, 16, 0, 0);
}

// Keep-alive (ext_vector/scalar operands ONLY — HIP float4 is a class type).
#define KEEP(x) asm volatile("" :: "v"(x))

// Agent-scope atomics: coherent at the device coherence point regardless of
// which XCD's L2 holds what (round-9 lesson: plain cross-XCD data through
// per-XCD L2s is NOT coherent within a dispatch; atomics are).
#define ASTORE(p, v) __hip_atomic_store((p), (v), __ATOMIC_RELAXED, __HIP_MEMORY_SCOPE_AGENT)
#define ALOAD(p)     __hip_atomic_load((p), __ATOMIC_RELAXED, __HIP_MEMORY_SCOPE_AGENT)

// ---------------------------------------------------------------------------
// prep: wT[n][k] = bf16(w[k][n]); zero out + the 8 per-batch completion
// counters (dispatch boundary makes these visible to fused).
// ---------------------------------------------------------------------------
__global__ __launch_bounds__(256) void prep_kernel(
    const float* __restrict__ w, ushort* __restrict__ wT,
    float* __restrict__ out, int out_size,
    unsigned* __restrict__ counters)
{
    int k  = threadIdx.x;          // D index
    int n0 = blockIdx.x * 4;       // P index base
    f32x4 wv = *(const f32x4*)(w + (size_t)k * PDIM + n0);
    wT[(size_t)(n0 + 0) * DDIM + k] = (ushort)f2bf(wv[0]);
    wT[(size_t)(n0 + 1) * DDIM + k] = (ushort)f2bf(wv[1]);
    wT[(size_t)(n0 + 2) * DDIM + k] = (ushort)f2bf(wv[2]);
    wT[(size_t)(n0 + 3) * DDIM + k] = (ushort)f2bf(wv[3]);
    int g = blockIdx.x * 256 + k;
    if (g < out_size) out[g] = 0.f;
    if (blockIdx.x == 0 && k < BDIM) counters[k] = 0u;
}

// ---------------------------------------------------------------------------
// proj v5: u_p/e_p = bf16(enc @ w + bias), MFMA 16x16x32 bf16.  (unchanged
// round-8: swizzled LDS wT tile, KEEP-pinned A batch, k-permuted ushort4
// stores.)
// ---------------------------------------------------------------------------
__global__ __launch_bounds__(256) void proj_kernel(
    const float* __restrict__ u_enc, const float* __restrict__ e_enc,
    const ushort* __restrict__ wT, const float* __restrict__ bias,
    ushort* __restrict__ u_p, ushort* __restrict__ e_p)
{
    __shared__ ushort lds_b[64 * 256];   // 32 KB, swizzled: byte = rl*512 + (cb ^ ((rl&7)<<4))

    int bid  = blockIdx.x;                 // 0..1023
    int lin  = (bid & 7) * 128 + (bid >> 3);
    int row0 = (lin >> 2) * 64;
    int col0 = (lin & 3) * 64;

    const float* A; ushort* C;
    if (row0 < BDIM * UDIM) { A = u_enc; C = u_p; }
    else                    { A = e_enc; C = e_p; row0 -= BDIM * UDIM; }

    int tid  = threadIdx.x;
    int wave = tid >> 6, lane = tid & 63;
    int m = lane & 15, quad = lane >> 4;

    // ---- stage wT rows [col0, col0+64) into LDS, swizzled source ----
    {
        int rl_base = wave * 16;
        int lr = lane >> 5;            // 0/1
        int cb = (lane & 31) * 16;     // 0..496
        #pragma unroll
        for (int j = 0; j < 8; ++j) {
            int rl = rl_base + 2 * j + lr;
            const ushort* src = wT + (size_t)(col0 + rl) * DDIM + ((cb ^ ((rl & 7) << 4)) >> 1);
            dma16(src, &lds_b[(size_t)(rl_base + 2 * j) * DDIM]);
        }
    }

    // ---- A strip: 16 x f32x4 batched into registers, KEEP-pinned ----
    const float* aptr = A + (size_t)(row0 + wave * 16 + m) * DDIM + quad * 8;
    f32x4 a[16];
    #pragma unroll
    for (int i = 0; i < 8; ++i) {
        a[2 * i]     = *(const f32x4*)(aptr + 32 * i);
        a[2 * i + 1] = *(const f32x4*)(aptr + 32 * i + 4);
    }
    #pragma unroll
    for (int i = 0; i < 16; ++i) KEEP(a[i]);

    asm volatile("s_waitcnt vmcnt(0)" ::: "memory");
    __syncthreads();

    int rowmask = (m & 7) << 4;        // swizzle term: B row = nt*16 + m -> row&7 = m&7
    f32x4 acc[4] = {};
    #pragma unroll
    for (int i = 0; i < 8; ++i) {
        bf16x8 af;
        af[0] = f2bf(a[2*i][0]);   af[1] = f2bf(a[2*i][1]);
        af[2] = f2bf(a[2*i][2]);   af[3] = f2bf(a[2*i][3]);
        af[4] = f2bf(a[2*i+1][0]); af[5] = f2bf(a[2*i+1][1]);
        af[6] = f2bf(a[2*i+1][2]); af[7] = f2bf(a[2*i+1][3]);
        #pragma unroll
        for (int nt = 0; nt < 4; ++nt) {
            int elem = (nt * 16 + m) * DDIM + (((quad * 16 + 64 * i) ^ rowmask) >> 1);
            bf16x8 bfr = *(const bf16x8*)(lds_b + elem);
            acc[nt] = __builtin_amdgcn_mfma_f32_16x16x32_bf16(af, bfr, acc[nt], 0, 0, 0);
        }
    }

    // k-permuted coalesced store: tile-local col (m*4 + nt), ushort4.
    #pragma unroll
    for (int r = 0; r < 4; ++r) {
        int row = row0 + wave * 16 + quad * 4 + r;
        u16x4 pk;
        #pragma unroll
        for (int nt = 0; nt < 4; ++nt)
            pk[nt] = (ushort)f2bf(acc[nt][r] + bias[col0 + nt * 16 + m]);
        *(u16x4*)(C + (size_t)row * PDIM + col0 + 4 * m) = pk;
    }
}

// ---------------------------------------------------------------------------
// fused v10: round-8 tile logic (e-perm LDS, pair/mask in regs, single drain)
// + MERGED FINISH via per-batch completion counter:
//   * partial sums stored with agent-scope atomic stores (coherent at the
//     device coherence point — no XCD-mapping assumption, round-9 lesson);
//   * each block release-increments counters[b]; the LAST 16 arrivals
//     (idx>=240) become finishers: spin (acquire) till 256, read partials
//     via agent atomic loads, MAC against enc, write an EXCLUSIVE 32-col
//     slice of out (no atomics, no zero-init needed).
// No deadlock: <=128 spinners << 1024 co-resident capacity; awaited blocks
// are independent and retire continuously.
// ---------------------------------------------------------------------------
__global__ __launch_bounds__(256) void fused_kernel(
    const ushort* __restrict__ u_p, const ushort* __restrict__ e_p,
    const float* __restrict__ pair_enc, const float* __restrict__ ue_mask,
    const float* __restrict__ bpp_w_p, const float* __restrict__ bpp_b_p,
    const float* __restrict__ u_enc, const float* __restrict__ e_enc,
    float* __restrict__ row_part /*[B][4][1024]*/,
    float* __restrict__ col_part /*[B][16][1024]*/,
    unsigned* __restrict__ counters, float* __restrict__ out)
{
    __shared__ ushort lds_e[64 * 256];   // 32 KB; finisher phase aliases it
    __shared__ float colred[4][64];      // 1 KB
    __shared__ unsigned bcast;

    int bid  = blockIdx.x;          // 0..2047
    int b    = bid & 7;             // batch <-> XCD (perf heuristic only)
    int tile = bid >> 3;            // 0..255
    int iu = tile >> 4, ie = tile & 15;
    int u0 = iu * 64, e0 = ie * 64;

    int tid  = threadIdx.x;
    int wave = tid >> 6, lane = tid & 63;
    int m = lane & 15, quad = lane >> 4;

    const float* pm = pair_enc + (size_t)b * UDIM * EDIM;
    const float* mm = ue_mask  + (size_t)b * UDIM * EDIM;
    const ushort* eb = e_p + (size_t)b * EDIM * PDIM;

    // ---- stage e-tile, permuted rows: LDS row rl <- e_p row e0+(rl&15)*4+(rl>>4) ----
    {
        int lr = lane >> 5;            // 0/1
        int cb = (lane & 31) * 16;     // byte-in-row 0..496
        #pragma unroll
        for (int j = 0; j < 8; ++j) {
            int rl = wave * 16 + 2 * j + lr;                 // DEST row (linear)
            int esrc = e0 + ((rl & 15) << 2) + (rl >> 4);    // permuted SOURCE row
            const ushort* src = eb + (size_t)esrc * PDIM + ((cb ^ ((rl & 7) << 4)) >> 1);
            dma16(src, &lds_e[(size_t)(wave * 16 + 2 * j) * PDIM]);
        }
    }

    // ---- af frags: 8x16B batched into regs, KEEP-pinned ----
    const ushort* Au = u_p + (size_t)b * UDIM * PDIM + (size_t)(u0 + wave * 16 + m) * PDIM + quad * 8;
    bf16x8 af[8];
    #pragma unroll
    for (int i = 0; i < 8; ++i) af[i] = *(const bf16x8*)(Au + 32 * i);
    #pragma unroll
    for (int i = 0; i < 8; ++i) KEEP(af[i]);

    // ---- pair/mask: 4+4 f32x4 direct to regs (e-perm makes them contiguous) ----
    const float* pmRow = pm + (size_t)(u0 + wave * 16 + quad * 4) * EDIM + e0 + 4 * m;
    const float* mmRow = mm + (size_t)(u0 + wave * 16 + quad * 4) * EDIM + e0 + 4 * m;
    f32x4 pv4[4], mv4[4];
    #pragma unroll
    for (int r = 0; r < 4; ++r) {
        pv4[r] = *(const f32x4*)(pmRow + (size_t)r * EDIM);
        mv4[r] = *(const f32x4*)(mmRow + (size_t)r * EDIM);
    }
    #pragma unroll
    for (int r = 0; r < 4; ++r) { KEEP(pv4[r]); KEEP(mv4[r]); }

    float bw = bpp_w_p[0], bb = bpp_b_p[0];

    asm volatile("s_waitcnt vmcnt(0)" ::: "memory");
    __syncthreads();

    // ---- MFMA loop, B frags from permuted+swizzled LDS ----
    int rowmask = (m & 7) << 4;
    f32x4 acc[4] = {};
    #pragma unroll
    for (int i = 0; i < 8; ++i) {
        #pragma unroll
        for (int nt = 0; nt < 4; ++nt) {
            int elem = (nt * 16 + m) * PDIM + (((quad * 16 + 64 * i) ^ rowmask) >> 1);
            bf16x8 bfr = *(const bf16x8*)(lds_e + elem);
            acc[nt] = __builtin_amdgcn_mfma_f32_16x16x32_bf16(af[i], bfr, acc[nt], 0, 0, 0);
        }
    }

    // ---- epilogue: gate + partial sums (acc[nt][r] <-> pv4[r][nt]) ----
    float rsum[4] = {0.f, 0.f, 0.f, 0.f};
    float csum[4] = {0.f, 0.f, 0.f, 0.f};
    #pragma unroll
    for (int r = 0; r < 4; ++r) {
        #pragma unroll
        for (int nt = 0; nt < 4; ++nt) {
            float mv = mv4[r][nt];
            float pvv = pv4[r][nt];
            float arg = bw * pvv + bb + mv * acc[nt][r];
            float s = mv / (1.f + __expf(-arg));
            rsum[r]  += s;
            csum[nt] += s;
        }
    }

    // Row partials: quad-lane reduce; unique slot (b, ie, u) -> agent atomic store.
    #pragma unroll
    for (int r = 0; r < 4; ++r) {
        float v = rsum[r];
        v += __shfl_xor(v, 1); v += __shfl_xor(v, 2);
        v += __shfl_xor(v, 4); v += __shfl_xor(v, 8);
        if (m == 0)
            ASTORE(&row_part[((size_t)b * 4 + ie / 4 * 0 + (ie & 3)) * 0 + ((size_t)b * 4 + (ie & 3)) * 0 + ((size_t)b * 16 + ie) * UDIM + u0 + wave * 16 + quad * 4 + r], v);
    }

    // Col partials: csum[nt] is actual e-col 4m+nt; cross-wave reduce -> store.
    #pragma unroll
    for (int nt = 0; nt < 4; ++nt) {
        float v = csum[nt];
        v += __shfl_xor(v, 16); v += __shfl_xor(v, 32);
        if (quad == 0) colred[wave][4 * m + nt] = v;
    }
    __syncthreads();

    if (tid < 64) {
        float v = colred[0][tid] + colred[1][tid] + colred[2][tid] + colred[3][tid];
        ASTORE(&col_part[((size_t)b * 16 + iu) * EDIM + e0 + tid], v);
    }

    // ---- completion counter: last 16 arrivals per batch do the finish ----
    __syncthreads();                 // all partial stores retired (vmcnt drained)
    if (tid == 0)
        bcast = __hip_atomic_fetch_add(&counters[b], 1u, __ATOMIC_ACQ_REL, __HIP_MEMORY_SCOPE_AGENT);
    __syncthreads();
    unsigned idx = bcast;
    if (idx < 240u) return;

    if (tid == 0) {
        while (__hip_atomic_load(&counters[b], __ATOMIC_ACQUIRE, __HIP_MEMORY_SCOPE_AGENT) < 256u)
            __builtin_amdgcn_s_sleep(8);
    }
    __syncthreads();

    // ---- finish slice fi = idx-240: half = fi>>3, d-cols (fi&7)*32..+31 ----
    int fi   = (int)idx - 240;       // 0..15
    int half = fi >> 3;
    int d0   = (fi & 7) * 32;
    const float* encb = (half ? e_enc : u_enc) + (size_t)b * UDIM * DDIM;

    float* s_lds = (float*)lds_e;            // 1024 floats (4 KB)
    float* red   = ((float*)lds_e) + 1024;   // 256 floats (1 KB)

    // s_lds[u] = summed partials (agent atomic loads: coherent regardless of
    // which XCD produced them).
    {
        int u = tid * 4;
        #pragma unroll
        for (int k = 0; k < 4; ++k) {
            float s = 0.f;
            if (half) {
                #pragma unroll
                for (int p = 0; p < 16; ++p)
                    s += ALOAD(&col_part[((size_t)b * 16 + p) * EDIM + u + k]);
            } else {
                #pragma unroll
                for (int p = 0; p < 16; ++p)
                    s += ALOAD(&row_part[((size_t)b * 16 + p) * UDIM + u + k]);
            }
            s_lds[u + k] = s;
        }
    }
    __syncthreads();

    int d  = d0 + (tid & 31);
    int ug = tid >> 5;               // 0..7, each handles 128 rows
    float facc = 0.f;
    #pragma unroll 8
    for (int u = ug * 128; u < ug * 128 + 128; ++u)
        facc += s_lds[u] * encb[(size_t)u * DDIM + d];
    red[ug * 32 + (tid & 31)] = facc;
    __syncthreads();

    if (tid < 32) {
        float v = 0.f;
        #pragma unroll
        for (int g = 0; g < 8; ++g) v += red[g * 32 + tid];
        out[(size_t)b * 2 * DDIM + half * DDIM + d0 + tid] = v;
    }
}

// ---------------------------------------------------------------------------
extern "C" void kernel_launch(void* const* d_in, const int* in_sizes, int n_in,
                              void* d_out, int out_size, void* d_ws, size_t ws_size,
                              hipStream_t stream)
{
    const float* u_enc    = (const float*)d_in[0];
    const float* e_enc    = (const float*)d_in[1];
    const float* pair_enc = (const float*)d_in[2];
    const float* ue_mask  = (const float*)d_in[3];
    const float* w_kernel = (const float*)d_in[4];
    const float* w_bias   = (const float*)d_in[5];
    const float* bpp_w    = (const float*)d_in[6];
    const float* bpp_b    = (const float*)d_in[7];
    float* out = (float*)d_out;

    // ws layout: u_p bf16 (4MB) | e_p bf16 (4MB) | wT bf16 (128KB) |
    //            row_part fp32 [B][16][1024] | col_part fp32 [B][16][1024] | counters
    ushort* u_p = (ushort*)d_ws;
    ushort* e_p = u_p + (size_t)BDIM * UDIM * PDIM;
    ushort* wT  = e_p + (size_t)BDIM * EDIM * PDIM;
    float* row_part = (float*)(wT + (size_t)DDIM * PDIM);
    float* col_part = row_part + (size_t)BDIM * 16 * UDIM;
    unsigned* counters = (unsigned*)(col_part + (size_t)BDIM * 16 * EDIM);

    prep_kernel<<<dim3(64), 256, 0, stream>>>(w_kernel, wT, out, out_size, counters);

    proj_kernel<<<dim3(1024), 256, 0, stream>>>(u_enc, e_enc, wT, w_bias, u_p, e_p);

    fused_kernel<<<dim3(2048), 256, 0, stream>>>(u_p, e_p, pair_enc, ue_mask,
                                                 bpp_w, bpp_b, u_enc, e_enc,
                                                 row_part, col_part, counters, out);
}

// Round 11
// 144.799 us; speedup vs baseline: 1.5673x; 1.5673x over previous
//
#include <hip/hip_runtime.h>

// Problem constants (SubOut_60206851555968): B=8, U=E=1024, D=P=256, fp32 in/out.
#define BDIM 8
#define UDIM 1024
#define EDIM 1024
#define DDIM 256
#define PDIM 256

typedef __attribute__((ext_vector_type(8))) short bf16x8;   // 8 bf16 = 4 VGPRs
typedef __attribute__((ext_vector_type(4))) float f32x4;    // clang ext_vector: legal in asm "v"
typedef __attribute__((ext_vector_type(4))) ushort u16x4;

__device__ __forceinline__ short f2bf(float x) {
    unsigned u = __float_as_uint(x);
    unsigned r = (u + 0x7FFFu + ((u >> 16) & 1u)) >> 16;   // RNE
    return (short)r;
}

// Async global->LDS DMA, 16B per lane. LDS dest = wave-uniform base + lane*16;
// global src is per-lane (swizzled/permuted LDS layouts = pre-permute the SOURCE).
__device__ __forceinline__ void dma16(const void* g, void* lds) {
    __builtin_amdgcn_global_load_lds(
        (const __attribute__((address_space(1))) unsigned*)g,
        (__attribute__((address_space(3))) unsigned*)lds, 16, 0, 0);
}

// Keep-alive (ext_vector/scalar operands ONLY — HIP float4 is a class type).
#define KEEP(x) asm volatile("" :: "v"(x))

// ---------------------------------------------------------------------------
// prep: wT[n][k] = bf16(w[k][n]); zero out.  (round-8 version)
// ---------------------------------------------------------------------------
__global__ __launch_bounds__(256) void prep_kernel(
    const float* __restrict__ w, ushort* __restrict__ wT,
    float* __restrict__ out, int out_size)
{
    int k  = threadIdx.x;          // D index
    int n0 = blockIdx.x * 4;       // P index base
    f32x4 wv = *(const f32x4*)(w + (size_t)k * PDIM + n0);
    wT[(size_t)(n0 + 0) * DDIM + k] = (ushort)f2bf(wv[0]);
    wT[(size_t)(n0 + 1) * DDIM + k] = (ushort)f2bf(wv[1]);
    wT[(size_t)(n0 + 2) * DDIM + k] = (ushort)f2bf(wv[2]);
    wT[(size_t)(n0 + 3) * DDIM + k] = (ushort)f2bf(wv[3]);
    int g = blockIdx.x * 256 + k;
    if (g < out_size) out[g] = 0.f;
}

// ---------------------------------------------------------------------------
// proj v6: u_p/e_p = bf16(enc @ w + bias), MFMA 16x16x32 bf16.
// NEW: 512 blocks, each owns ONE A-strip and TWO col-tiles. The 16 f32x4
// A batch is loaded once (KEEP-pinned) and reused for both tiles -> enc
// HBM read drops 4x -> 2x (-17MB). wT tile staged per col-tile into
// swizzled LDS as before; k-permuted coalesced ushort4 stores unchanged.
// Round-10's completion-counter merge REVERTED (agent-scope release per
// block = per-block L2 writeback, 148.8 -> 226.9 regression).
// ---------------------------------------------------------------------------
__global__ __launch_bounds__(256) void proj_kernel(
    const float* __restrict__ u_enc, const float* __restrict__ e_enc,
    const ushort* __restrict__ wT, const float* __restrict__ bias,
    ushort* __restrict__ u_p, ushort* __restrict__ e_p)
{
    __shared__ ushort lds_b[64 * 256];   // 32 KB, swizzled: byte = rl*512 + (cb ^ ((rl&7)<<4))

    int bid  = blockIdx.x;                 // 0..511
    int lin  = (bid & 7) * 64 + (bid >> 3);
    int row0 = (lin >> 1) * 64;            // strip 0..255
    int cp   = (lin & 1) * 2;              // col-tile pair base: tiles {cp, cp+1}

    const float* A; ushort* C;
    if (row0 < BDIM * UDIM) { A = u_enc; C = u_p; }
    else                    { A = e_enc; C = e_p; row0 -= BDIM * UDIM; }

    int tid  = threadIdx.x;
    int wave = tid >> 6, lane = tid & 63;
    int m = lane & 15, quad = lane >> 4;

    // ---- A strip: 16 x f32x4 batched into registers ONCE, KEEP-pinned ----
    const float* aptr = A + (size_t)(row0 + wave * 16 + m) * DDIM + quad * 8;
    f32x4 a[16];
    #pragma unroll
    for (int i = 0; i < 8; ++i) {
        a[2 * i]     = *(const f32x4*)(aptr + 32 * i);
        a[2 * i + 1] = *(const f32x4*)(aptr + 32 * i + 4);
    }
    #pragma unroll
    for (int i = 0; i < 16; ++i) KEEP(a[i]);

    int rowmask = (m & 7) << 4;        // swizzle term: B row = nt*16 + m -> row&7 = m&7

    for (int s = 0; s < 2; ++s) {
        int col0 = (cp + s) * 64;
        if (s) __syncthreads();        // prior tile's LDS readers done

        // ---- stage wT rows [col0, col0+64) into LDS, swizzled source ----
        {
            int lr = lane >> 5;            // 0/1
            int cb = (lane & 31) * 16;     // 0..496
            #pragma unroll
            for (int j = 0; j < 8; ++j) {
                int rl = wave * 16 + 2 * j + lr;
                const ushort* src = wT + (size_t)(col0 + rl) * DDIM + ((cb ^ ((rl & 7) << 4)) >> 1);
                dma16(src, &lds_b[(size_t)(wave * 16 + 2 * j) * DDIM]);
            }
        }
        asm volatile("s_waitcnt vmcnt(0)" ::: "memory");
        __syncthreads();

        f32x4 acc[4] = {};
        #pragma unroll
        for (int i = 0; i < 8; ++i) {
            bf16x8 af;
            af[0] = f2bf(a[2*i][0]);   af[1] = f2bf(a[2*i][1]);
            af[2] = f2bf(a[2*i][2]);   af[3] = f2bf(a[2*i][3]);
            af[4] = f2bf(a[2*i+1][0]); af[5] = f2bf(a[2*i+1][1]);
            af[6] = f2bf(a[2*i+1][2]); af[7] = f2bf(a[2*i+1][3]);
            #pragma unroll
            for (int nt = 0; nt < 4; ++nt) {
                int elem = (nt * 16 + m) * DDIM + (((quad * 16 + 64 * i) ^ rowmask) >> 1);
                bf16x8 bfr = *(const bf16x8*)(lds_b + elem);
                acc[nt] = __builtin_amdgcn_mfma_f32_16x16x32_bf16(af, bfr, acc[nt], 0, 0, 0);
            }
        }

        // k-permuted coalesced store: tile-local col (m*4 + nt), ushort4.
        #pragma unroll
        for (int r = 0; r < 4; ++r) {
            int row = row0 + wave * 16 + quad * 4 + r;
            u16x4 pk;
            #pragma unroll
            for (int nt = 0; nt < 4; ++nt)
                pk[nt] = (ushort)f2bf(acc[nt][r] + bias[col0 + nt * 16 + m]);
            *(u16x4*)(C + (size_t)row * PDIM + col0 + 4 * m) = pk;
        }
    }
}

// ---------------------------------------------------------------------------
// fused v9 (round-8 known-good): op = u_p . e_p (MFMA), gate, partial sums.
// e-row-permuted LDS staging (epilogue operands contiguous -> pair/mask
// direct-to-register f32x4), single pre-drain vmcnt batch, 33KB LDS ->
// 4 blocks/CU, non-atomic partial stores to disjoint slots.
// ---------------------------------------------------------------------------
__global__ __launch_bounds__(256) void fused_kernel(
    const ushort* __restrict__ u_p, const ushort* __restrict__ e_p,
    const float* __restrict__ pair_enc, const float* __restrict__ ue_mask,
    const float* __restrict__ bpp_w_p, const float* __restrict__ bpp_b_p,
    float* __restrict__ row_part /*[B][16][1024]*/,
    float* __restrict__ col_part /*[B][16][1024]*/)
{
    __shared__ ushort lds_e[64 * 256];   // 32 KB, e-row-permuted + col-swizzled
    __shared__ float colred[4][64];      // 1 KB

    int bid  = blockIdx.x;          // 0..2047
    int b    = bid & 7;             // batch <-> XCD (FETCH win, kept)
    int tile = bid >> 3;            // 0..255
    int iu = tile >> 4, ie = tile & 15;
    int u0 = iu * 64, e0 = ie * 64;

    int tid  = threadIdx.x;
    int wave = tid >> 6, lane = tid & 63;
    int m = lane & 15, quad = lane >> 4;

    const float* pm = pair_enc + (size_t)b * UDIM * EDIM;
    const float* mm = ue_mask  + (size_t)b * UDIM * EDIM;
    const ushort* eb = e_p + (size_t)b * EDIM * PDIM;

    // ---- stage e-tile, permuted rows: LDS row rl <- e_p row e0+(rl&15)*4+(rl>>4) ----
    {
        int lr = lane >> 5;            // 0/1
        int cb = (lane & 31) * 16;     // byte-in-row 0..496
        #pragma unroll
        for (int j = 0; j < 8; ++j) {
            int rl = wave * 16 + 2 * j + lr;                 // DEST row (linear)
            int esrc = e0 + ((rl & 15) << 2) + (rl >> 4);    // permuted SOURCE row
            const ushort* src = eb + (size_t)esrc * PDIM + ((cb ^ ((rl & 7) << 4)) >> 1);
            dma16(src, &lds_e[(size_t)(wave * 16 + 2 * j) * PDIM]);
        }
    }

    // ---- af frags: 8x16B batched into regs, KEEP-pinned ----
    const ushort* Au = u_p + (size_t)b * UDIM * PDIM + (size_t)(u0 + wave * 16 + m) * PDIM + quad * 8;
    bf16x8 af[8];
    #pragma unroll
    for (int i = 0; i < 8; ++i) af[i] = *(const bf16x8*)(Au + 32 * i);
    #pragma unroll
    for (int i = 0; i < 8; ++i) KEEP(af[i]);

    // ---- pair/mask: 4+4 f32x4 direct to regs (e-perm makes them contiguous) ----
    const float* pmRow = pm + (size_t)(u0 + wave * 16 + quad * 4) * EDIM + e0 + 4 * m;
    const float* mmRow = mm + (size_t)(u0 + wave * 16 + quad * 4) * EDIM + e0 + 4 * m;
    f32x4 pv4[4], mv4[4];
    #pragma unroll
    for (int r = 0; r < 4; ++r) {
        pv4[r] = *(const f32x4*)(pmRow + (size_t)r * EDIM);
        mv4[r] = *(const f32x4*)(mmRow + (size_t)r * EDIM);
    }
    #pragma unroll
    for (int r = 0; r < 4; ++r) { KEEP(pv4[r]); KEEP(mv4[r]); }

    float bw = bpp_w_p[0], bb = bpp_b_p[0];

    asm volatile("s_waitcnt vmcnt(0)" ::: "memory");
    __syncthreads();

    // ---- MFMA loop, B frags from permuted+swizzled LDS ----
    int rowmask = (m & 7) << 4;
    f32x4 acc[4] = {};
    #pragma unroll
    for (int i = 0; i < 8; ++i) {
        #pragma unroll
        for (int nt = 0; nt < 4; ++nt) {
            int elem = (nt * 16 + m) * PDIM + (((quad * 16 + 64 * i) ^ rowmask) >> 1);
            bf16x8 bfr = *(const bf16x8*)(lds_e + elem);
            acc[nt] = __builtin_amdgcn_mfma_f32_16x16x32_bf16(af[i], bfr, acc[nt], 0, 0, 0);
        }
    }

    // ---- epilogue: gate + partial sums (acc[nt][r] <-> pv4[r][nt]) ----
    float rsum[4] = {0.f, 0.f, 0.f, 0.f};
    float csum[4] = {0.f, 0.f, 0.f, 0.f};
    #pragma unroll
    for (int r = 0; r < 4; ++r) {
        #pragma unroll
        for (int nt = 0; nt < 4; ++nt) {
            float mv = mv4[r][nt];
            float pvv = pv4[r][nt];
            float arg = bw * pvv + bb + mv * acc[nt][r];
            float s = mv / (1.f + __expf(-arg));
            rsum[r]  += s;
            csum[nt] += s;
        }
    }

    // Row partials: quad-lane reduce; unique slot (b, ie, u) -> plain store.
    #pragma unroll
    for (int r = 0; r < 4; ++r) {
        float v = rsum[r];
        v += __shfl_xor(v, 1); v += __shfl_xor(v, 2);
        v += __shfl_xor(v, 4); v += __shfl_xor(v, 8);
        if (m == 0)
            row_part[((size_t)b * 16 + ie) * UDIM + u0 + wave * 16 + quad * 4 + r] = v;
    }

    // Col partials: csum[nt] is actual e-col 4m+nt; cross-wave reduce -> store.
    #pragma unroll
    for (int nt = 0; nt < 4; ++nt) {
        float v = csum[nt];
        v += __shfl_xor(v, 16); v += __shfl_xor(v, 32);
        if (quad == 0) colred[wave][4 * m + nt] = v;
    }
    __syncthreads();

    if (tid < 64) {
        float v = colred[0][tid] + colred[1][tid] + colred[2][tid] + colred[3][tid];
        col_part[((size_t)b * 16 + iu) * EDIM + e0 + tid] = v;
    }
}

// ---------------------------------------------------------------------------
// finish v4 (round-8): out[b,0:256] = (sum_p row_part[b][p]) @ u_enc[b];
//                      out[b,256:512] = (sum_p col_part[b][p]) @ e_enc[b].
// ---------------------------------------------------------------------------
__global__ __launch_bounds__(256) void finish_kernel(
    const float* __restrict__ u_enc, const float* __restrict__ e_enc,
    const float* __restrict__ row_part, const float* __restrict__ col_part,
    float* __restrict__ out)
{
    __shared__ float s_lds[32];

    int b = blockIdx.x;
    int half = blockIdx.y;
    int chunk = blockIdx.z;        // 0..31
    int d = threadIdx.x;

    const float* enc  = half ? e_enc   : u_enc;
    const float* part = half ? col_part : row_part;

    int base = chunk * 32;
    if (d < 32) {
        float s = 0.f;
        #pragma unroll
        for (int p = 0; p < 16; ++p)
            s += part[((size_t)b * 16 + p) * UDIM + base + d];
        s_lds[d] = s;
    }

    float ev[32];
    #pragma unroll
    for (int j = 0; j < 32; ++j)
        ev[j] = enc[(size_t)(b * UDIM + base + j) * DDIM + d];
    #pragma unroll
    for (int j = 0; j < 32; ++j) KEEP(ev[j]);

    __syncthreads();

    float acc = 0.f;
    #pragma unroll
    for (int j = 0; j < 32; ++j)
        acc += s_lds[j] * ev[j];

    atomicAdd(&out[(size_t)b * 2 * DDIM + half * DDIM + d], acc);
}

// ---------------------------------------------------------------------------
extern "C" void kernel_launch(void* const* d_in, const int* in_sizes, int n_in,
                              void* d_out, int out_size, void* d_ws, size_t ws_size,
                              hipStream_t stream)
{
    const float* u_enc    = (const float*)d_in[0];
    const float* e_enc    = (const float*)d_in[1];
    const float* pair_enc = (const float*)d_in[2];
    const float* ue_mask  = (const float*)d_in[3];
    const float* w_kernel = (const float*)d_in[4];
    const float* w_bias   = (const float*)d_in[5];
    const float* bpp_w    = (const float*)d_in[6];
    const float* bpp_b    = (const float*)d_in[7];
    float* out = (float*)d_out;

    // ws layout: u_p bf16 (4MB) | e_p bf16 (4MB) | wT bf16 (128KB) |
    //            row_part fp32 [B][16][1024] (512KB) | col_part fp32 [B][16][1024] (512KB)
    ushort* u_p = (ushort*)d_ws;
    ushort* e_p = u_p + (size_t)BDIM * UDIM * PDIM;
    ushort* wT  = e_p + (size_t)BDIM * EDIM * PDIM;
    float* row_part = (float*)(wT + (size_t)DDIM * PDIM);
    float* col_part = row_part + (size_t)BDIM * 16 * UDIM;

    prep_kernel<<<dim3(64), 256, 0, stream>>>(w_kernel, wT, out, out_size);

    proj_kernel<<<dim3(512), 256, 0, stream>>>(u_enc, e_enc, wT, w_bias, u_p, e_p);

    fused_kernel<<<dim3(2048), 256, 0, stream>>>(u_p, e_p, pair_enc, ue_mask,
                                                 bpp_w, bpp_b, row_part, col_part);

    finish_kernel<<<dim3(BDIM, 2, 32), 256, 0, stream>>>(u_enc, e_enc, row_part, col_part, out);
}